// Round 2
// baseline (912.535 us; speedup 1.0000x reference)
//
#include <hip/hip_runtime.h>
#include <hip/hip_bf16.h>

#define BATCH  16
#define CCH    128
#define TDIM   16384
#define MROWS  256                 // 2C
#define BK     32
#define LDSP   40                  // padded LDS row stride (elements)
#define GRAM   (MROWS * MROWS)     // 65536

typedef __attribute__((ext_vector_type(8))) short bf16x8;
typedef __attribute__((ext_vector_type(4))) float f32x4;
typedef __attribute__((ext_vector_type(4))) unsigned short u16x4;

__device__ __forceinline__ unsigned short f2bf(float x) {
  // RTNE fp32 -> bf16 (inputs are finite normals; no NaN path needed)
  unsigned int u = __float_as_uint(x);
  u += 0x7fffu + ((u >> 16) & 1u);
  return (unsigned short)(u >> 16);
}

// Barrier WITHOUT the compiler's vmcnt(0) drain: only LDS ops must be
// visible across the barrier; global loads (register dests) need no
// cross-wave ordering. Keeps prefetch loads in flight across the barrier
// (T4: never drain vmcnt to 0 in the main loop).
__device__ __forceinline__ void pipe_barrier() {
  asm volatile("s_waitcnt lgkmcnt(0)" ::: "memory");
  __builtin_amdgcn_s_barrier();
  asm volatile("" ::: "memory");
}

__device__ __forceinline__ void load_step(
    f32x4 (&v)[4], const float* const (&rowptr)[4], int s)
{
  #pragma unroll
  for (int j = 0; j < 4; ++j)
    v[j] = *(const f32x4*)(rowptr[j] + s * BK);
}

__device__ __forceinline__ void stage_step(
    unsigned short (&buf)[MROWS][LDSP], const f32x4 (&v)[4],
    const int (&rowidx)[4], const int (&kq4)[4])
{
  #pragma unroll
  for (int j = 0; j < 4; ++j) {
    u16x4 p;
    p.x = f2bf(v[j].x); p.y = f2bf(v[j].y); p.z = f2bf(v[j].z); p.w = f2bf(v[j].w);
    *(u16x4*)&buf[rowidx[j]][kq4[j]] = p;
  }
}

__device__ __forceinline__ void compute_step(
    const unsigned short (&buf)[MROWS][LDSP],
    f32x4 (&acc)[4][8], int wr, int wc, int llo, int koff)
{
  bf16x8 af[4], bfr[8];
  #pragma unroll
  for (int i = 0; i < 4; ++i)
    af[i] = *(const bf16x8*)&buf[wr * 64 + i * 16 + llo][koff];
  #pragma unroll
  for (int j = 0; j < 8; ++j)
    bfr[j] = *(const bf16x8*)&buf[wc * 128 + j * 16 + llo][koff];
  #pragma unroll
  for (int i = 0; i < 4; ++i)
    #pragma unroll
    for (int j = 0; j < 8; ++j)
      acc[i][j] = __builtin_amdgcn_mfma_f32_16x16x32_bf16(af[i], bfr[j], acc[i][j], 0, 0, 0);
}

// Computes partial gram of M_b = [s_b; t_b] (256 x T) over one K-chunk.
// atomic_mode=0: store partial to outp + blockIdx*GRAM
// atomic_mode=1: atomicAdd into outp + b*GRAM (small-ws path)
// launch_bounds(512,4): 4 waves/EU min -> VGPR<=128 -> 2 blocks/CU when
// grid = 512 (TLP overlap: one block computes while the other waits).
__global__ __launch_bounds__(512, 4) void gram_kernel(
    const float* __restrict__ fs, const float* __restrict__ ft,
    float* __restrict__ outp, int atomic_mode, int nchunk, int kc)
{
  __shared__ __attribute__((aligned(16))) unsigned short sm[2][MROWS][LDSP];

  const int tid   = threadIdx.x;
  const int bidx  = blockIdx.x;
  const int b     = bidx / nchunk;
  const int chunk = bidx - b * nchunk;
  const int kbase = chunk * kc;
  const int nstep = kc >> 5;       // kc / BK

  const int lane = tid & 63;
  const int w    = tid >> 6;     // wave 0..7
  const int wr   = w & 3;        // row-tile group: rows [wr*64, wr*64+64)
  const int wc   = w >> 2;       // col-tile group: cols [wc*128, wc*128+128)
  const int lhi  = lane >> 4;    // 0..3
  const int llo  = lane & 15;
  const int koff = lhi * 8;      // k offset of this lane's 8 bf16 (A/B layout)

  // staging assignment: idx = j*512+tid -> row = idx>>3, 8 float4 per row
  const float* rowptr[4];
  int rowidx[4], kq4[4];
  #pragma unroll
  for (int j = 0; j < 4; ++j) {
    int idx = j * 512 + tid;
    int row = idx >> 3;
    int kq  = idx & 7;
    rowidx[j] = row;
    kq4[j]    = kq * 4;
    const float* base = (row < CCH)
        ? (fs + (size_t)(b * CCH + row) * TDIM)
        : (ft + (size_t)(b * CCH + (row - CCH)) * TDIM);
    rowptr[j] = base + kbase + kq * 4;
  }

  f32x4 acc[4][8];
  #pragma unroll
  for (int i = 0; i < 4; ++i)
    #pragma unroll
    for (int j = 0; j < 8; ++j)
      acc[i][j] = (f32x4){0.f, 0.f, 0.f, 0.f};

  // -------- depth-2 software pipeline --------
  // Named register buffers va/vb (static indexing only — rule #20).
  f32x4 va[4], vb[4];
  load_step(va, rowptr, 0);
  load_step(vb, rowptr, 1);
  stage_step(sm[0], va, rowidx, kq4);   // compiler waits va only (vmcnt counted)
  pipe_barrier();

  #pragma unroll 1
  for (int s = 0; s < nstep - 2; s += 2) {
    // even step s: compute sm[0], stage vb(=step s+1)->sm[1], prefetch va=step s+2
    load_step(va, rowptr, s + 2);
    compute_step(sm[0], acc, wr, wc, llo, koff);
    stage_step(sm[1], vb, rowidx, kq4);
    pipe_barrier();
    // odd step s+1: compute sm[1], stage va(=step s+2)->sm[0], prefetch vb=step s+3
    load_step(vb, rowptr, s + 3);
    compute_step(sm[1], acc, wr, wc, llo, koff);
    stage_step(sm[0], va, rowidx, kq4);
    pipe_barrier();
  }
  // step nstep-2: compute sm[0], stage vb(=step nstep-1)->sm[1]
  compute_step(sm[0], acc, wr, wc, llo, koff);
  stage_step(sm[1], vb, rowidx, kq4);
  pipe_barrier();
  // step nstep-1: compute only
  compute_step(sm[1], acc, wr, wc, llo, koff);

  // epilogue: write partial gram
  // C/D layout (m89/m91 verified): col = lane&15, row = (lane>>4)*4 + reg
  if (atomic_mode) {
    float* out = outp + (size_t)b * GRAM;
    #pragma unroll
    for (int i = 0; i < 4; ++i) {
      int row0 = wr * 64 + i * 16 + lhi * 4;
      #pragma unroll
      for (int j = 0; j < 8; ++j) {
        int col = wc * 128 + j * 16 + llo;
        #pragma unroll
        for (int r = 0; r < 4; ++r)
          atomicAdd(&out[(size_t)(row0 + r) * MROWS + col], acc[i][j][r]);
      }
    }
  } else {
    float* out = outp + (size_t)bidx * GRAM;
    #pragma unroll
    for (int i = 0; i < 4; ++i) {
      int row0 = wr * 64 + i * 16 + lhi * 4;
      #pragma unroll
      for (int j = 0; j < 8; ++j) {
        int col = wc * 128 + j * 16 + llo;
        #pragma unroll
        for (int r = 0; r < 4; ++r)
          out[(size_t)(row0 + r) * MROWS + col] = acc[i][j][r];
      }
    }
  }
}

// One block per batch: inverse norms from gram diagonal (sum over nchunk slices)
__global__ __launch_bounds__(256) void norms_kernel(
    const float* __restrict__ gram, float* __restrict__ norms, int nchunk)
{
  int b = blockIdx.x;
  int d = threadIdx.x;  // 0..255
  float g = 0.f;
  int c = 0;
  for (; c + 3 < nchunk; c += 4) {   // 4 independent loads in flight
    float g0 = gram[(size_t)(b * nchunk + c + 0) * GRAM + (size_t)d * (MROWS + 1)];
    float g1 = gram[(size_t)(b * nchunk + c + 1) * GRAM + (size_t)d * (MROWS + 1)];
    float g2 = gram[(size_t)(b * nchunk + c + 2) * GRAM + (size_t)d * (MROWS + 1)];
    float g3 = gram[(size_t)(b * nchunk + c + 3) * GRAM + (size_t)d * (MROWS + 1)];
    g += (g0 + g1) + (g2 + g3);
  }
  for (; c < nchunk; ++c)
    g += gram[(size_t)(b * nchunk + c) * GRAM + (size_t)d * (MROWS + 1)];
  float n = sqrtf(fmaxf(g, 0.f));
  n = fmaxf(n, 1e-12f);   // F.normalize eps
  norms[b * MROWS + d] = 1.0f / n;
}

// grid = BATCH*64; each block handles 1024 gram elements of one batch
__global__ __launch_bounds__(256) void loss_kernel(
    const float* __restrict__ gram, const float* __restrict__ norms,
    float* __restrict__ out, int nchunk)
{
  int b     = blockIdx.x >> 6;
  int strip = blockIdx.x & 63;
  int e0    = strip * 1024 + threadIdx.x * 4;
  const float* nb = norms + b * MROWS;
  const float* gp = gram + (size_t)b * nchunk * GRAM + e0;

  f32x4 g = (f32x4){0.f, 0.f, 0.f, 0.f};
  int c = 0;
  for (; c + 3 < nchunk; c += 4) {   // 4 independent loads in flight
    f32x4 v0 = *(const f32x4*)(gp + (size_t)(c + 0) * GRAM);
    f32x4 v1 = *(const f32x4*)(gp + (size_t)(c + 1) * GRAM);
    f32x4 v2 = *(const f32x4*)(gp + (size_t)(c + 2) * GRAM);
    f32x4 v3 = *(const f32x4*)(gp + (size_t)(c + 3) * GRAM);
    g += (v0 + v1) + (v2 + v3);
  }
  for (; c < nchunk; ++c)
    g += *(const f32x4*)(gp + (size_t)c * GRAM);

  int i  = e0 >> 8;
  int j0 = e0 & 255;
  float ri = nb[i];
  float accl = 0.f;
  #pragma unroll
  for (int q = 0; q < 4; ++q) {
    int j = j0 + q;
    float gh = g[q] * ri * nb[j];
    // w_i*w_j: +1 within ss / tt blocks, -1 in st / ts blocks
    float sgn = ((i < CCH) == (j < CCH)) ? 1.f : -1.f;
    accl += sgn * gh * gh;
  }
  // block reduction
  #pragma unroll
  for (int off = 32; off > 0; off >>= 1)
    accl += __shfl_down(accl, off, 64);
  __shared__ float red[4];
  if ((threadIdx.x & 63) == 0) red[threadIdx.x >> 6] = accl;
  __syncthreads();
  if (threadIdx.x == 0) {
    float t = red[0] + red[1] + red[2] + red[3];
    atomicAdd(out, t * (1.0f / (float)(BATCH * CCH * CCH)));
  }
}

extern "C" void kernel_launch(void* const* d_in, const int* in_sizes, int n_in,
                              void* d_out, int out_size, void* d_ws, size_t ws_size,
                              hipStream_t stream) {
  const float* fs = (const float*)d_in[0];
  const float* ft = (const float*)d_in[1];
  float* out = (float*)d_out;
  float* wsf = (float*)d_ws;

  float* norms = wsf;            // 16*256 floats
  float* gram  = wsf + 4096;     // partials or accumulated gram

  const size_t need32 = ((size_t)4096 + (size_t)BATCH * 32 * GRAM) * 4;  // ~134 MB
  const size_t need16 = ((size_t)4096 + (size_t)BATCH * 16 * GRAM) * 4;  // ~67 MB

  int nchunk, atomic_mode;
  if (ws_size >= need32)      { nchunk = 32; atomic_mode = 0; }  // 2 blocks/CU
  else if (ws_size >= need16) { nchunk = 16; atomic_mode = 0; }
  else                        { nchunk = 16; atomic_mode = 1; }
  const int kc = TDIM / nchunk;
  const int nred = atomic_mode ? 1 : nchunk;

  (void)hipMemsetAsync(d_out, 0, sizeof(float), stream);
  if (atomic_mode)
    (void)hipMemsetAsync(gram, 0, (size_t)BATCH * GRAM * sizeof(float), stream);

  gram_kernel<<<dim3(BATCH * nchunk), dim3(512), 0, stream>>>(fs, ft, gram, atomic_mode, nchunk, kc);
  norms_kernel<<<dim3(BATCH), dim3(256), 0, stream>>>(gram, norms, nred);
  loss_kernel<<<dim3(BATCH * 64), dim3(256), 0, stream>>>(gram, norms, out, nred);
}

// Round 3
// 355.253 us; speedup vs baseline: 2.5687x; 2.5687x over previous
//
#include <hip/hip_runtime.h>
#include <hip/hip_bf16.h>

#define BATCH  16
#define CCH    128
#define TDIM   16384
#define MROWS  256                 // 2C
#define NCHUNK 16
#define KC     (TDIM / NCHUNK)     // 1024
#define BK     32
#define NSTEP  (KC / BK)           // 32
#define PIPE   4                   // LDS pipeline depth (buffers)
#define BUFFB  32768u              // bytes per buffer: 256 rows * 32 f32 * 4B
#define LDSBYTES (PIPE * BUFFB)    // 128 KiB dynamic LDS
#define GRAM   (MROWS * MROWS)     // 65536

typedef __attribute__((ext_vector_type(8))) short bf16x8;
typedef __attribute__((ext_vector_type(4))) float f32x4;
typedef const __attribute__((address_space(1))) unsigned int* gptr_t;
typedef __attribute__((address_space(3))) unsigned int* lptr_t;

// LDS layout per buffer: row-major [256][32] fp32, 128B row stride, NO pad
// (global_load_lds needs linear dest). Bank-conflict fix is an XOR swizzle
// of the 16B chunk index with (row&7), applied BOTH at the global source
// (inverse permutation, stays within the row's 128B -> coalescing kept)
// and at the LDS read (rule #21: both-sides-or-neither).

__device__ __forceinline__ void issue_stage(
    char* smraw, const float* const (&gsrc)[4], int tid, int stage)
{
  unsigned base = (unsigned)(stage & (PIPE - 1)) * BUFFB;
  #pragma unroll
  for (int j = 0; j < 4; ++j) {
    const float* g = gsrc[j] + (size_t)stage * BK;
    char* l = smraw + base + (unsigned)(j * 512 + tid) * 16u;
    __builtin_amdgcn_global_load_lds((gptr_t)g, (lptr_t)l, 16, 0, 0);
  }
}

// read one MFMA fragment (8 bf16 along K) from the fp32 swizzled buffer
__device__ __forceinline__ bf16x8 frag_from_f32(const float* bp, int row, int lhi) {
  const int r7 = row & 7;
  const f32x4* pr = (const f32x4*)(bp + row * 32);
  f32x4 lo = pr[(2 * lhi)     ^ r7];
  f32x4 hi = pr[(2 * lhi + 1) ^ r7];
  union { unsigned u[4]; bf16x8 v; } o;
  asm("v_cvt_pk_bf16_f32 %0, %1, %2" : "=v"(o.u[0]) : "v"(lo.x), "v"(lo.y));
  asm("v_cvt_pk_bf16_f32 %0, %1, %2" : "=v"(o.u[1]) : "v"(lo.z), "v"(lo.w));
  asm("v_cvt_pk_bf16_f32 %0, %1, %2" : "=v"(o.u[2]) : "v"(hi.x), "v"(hi.y));
  asm("v_cvt_pk_bf16_f32 %0, %1, %2" : "=v"(o.u[3]) : "v"(hi.z), "v"(hi.w));
  return o.v;
}

__device__ __forceinline__ void compute_step(
    const float* bp, f32x4 (&acc)[4][8], int wr, int wc, int llo, int lhi)
{
  bf16x8 af[4], bfr[8];
  #pragma unroll
  for (int i = 0; i < 4; ++i)
    af[i] = frag_from_f32(bp, wr * 64 + i * 16 + llo, lhi);
  #pragma unroll
  for (int j = 0; j < 8; ++j)
    bfr[j] = frag_from_f32(bp, wc * 128 + j * 16 + llo, lhi);
  #pragma unroll
  for (int i = 0; i < 4; ++i)
    #pragma unroll
    for (int j = 0; j < 8; ++j)
      acc[i][j] = __builtin_amdgcn_mfma_f32_16x16x32_bf16(af[i], bfr[j], acc[i][j], 0, 0, 0);
}

// Partial gram of M_b = [s_b; t_b] (256 x T) over one K-chunk.
// atomic_mode=0: store partial to outp + blockIdx*GRAM
// atomic_mode=1: atomicAdd into outp + b*GRAM (small-ws fallback)
__global__ __launch_bounds__(512, 2) void gram_kernel(
    const float* __restrict__ fs, const float* __restrict__ ft,
    float* __restrict__ outp, int atomic_mode)
{
  extern __shared__ __attribute__((aligned(16))) char smraw[];

  const int tid   = threadIdx.x;
  const int bidx  = blockIdx.x;
  const int b     = bidx / NCHUNK;
  const int chunk = bidx - b * NCHUNK;
  const int kbase = chunk * KC;

  const int lane = tid & 63;
  const int w    = tid >> 6;     // wave 0..7
  const int wr   = w & 3;        // row-tile group: rows [wr*64, wr*64+64)
  const int wc   = w >> 2;       // col-tile group: cols [wc*128, wc*128+128)
  const int lhi  = lane >> 4;    // 0..3  (selects 8-float K slice)
  const int llo  = lane & 15;

  // staging: idx = j*512+tid -> row = idx>>3, chunk-within-step kq (swizzled)
  const float* gsrc[4];
  #pragma unroll
  for (int j = 0; j < 4; ++j) {
    int idx = j * 512 + tid;
    int row = idx >> 3;
    int kq  = (idx & 7) ^ (row & 7);   // inverse of the read-side XOR swizzle
    const float* base = (row < CCH)
        ? (fs + (size_t)(b * CCH + row) * TDIM)
        : (ft + (size_t)(b * CCH + (row - CCH)) * TDIM);
    gsrc[j] = base + kbase + kq * 4;
  }

  f32x4 acc[4][8];
  #pragma unroll
  for (int i = 0; i < 4; ++i)
    #pragma unroll
    for (int j = 0; j < 8; ++j)
      acc[i][j] = (f32x4){0.f, 0.f, 0.f, 0.f};

  // prologue: fill the 4-deep DMA pipeline
  #pragma unroll
  for (int p = 0; p < PIPE; ++p)
    issue_stage(smraw, gsrc, tid, p);

  #pragma unroll 1
  for (int s = 0; s < NSTEP; ++s) {
    // wait until this step's buffer has landed; keep later stages in flight
    if (s <= NSTEP - 4)      asm volatile("s_waitcnt vmcnt(12)" ::: "memory");
    else if (s == NSTEP - 3) asm volatile("s_waitcnt vmcnt(8)"  ::: "memory");
    else if (s == NSTEP - 2) asm volatile("s_waitcnt vmcnt(4)"  ::: "memory");
    else                     asm volatile("s_waitcnt vmcnt(0)"  ::: "memory");
    __builtin_amdgcn_s_barrier();      // all waves' DMA for buf s landed
    asm volatile("" ::: "memory");

    const float* bp = (const float*)(smraw + (unsigned)(s & (PIPE - 1)) * BUFFB);
    compute_step(bp, acc, wr, wc, llo, lhi);

    asm volatile("s_waitcnt lgkmcnt(0)" ::: "memory");  // my LDS reads done
    __builtin_amdgcn_s_barrier();      // everyone done reading buf s
    asm volatile("" ::: "memory");

    if (s + PIPE < NSTEP)
      issue_stage(smraw, gsrc, tid, s + PIPE);   // refill slot (s&3)
  }

  // epilogue: write partial gram
  // C/D layout (m89/m91 verified): col = lane&15, row = (lane>>4)*4 + reg
  if (atomic_mode) {
    float* out = outp + (size_t)b * GRAM;
    #pragma unroll
    for (int i = 0; i < 4; ++i) {
      int row0 = wr * 64 + i * 16 + lhi * 4;
      #pragma unroll
      for (int j = 0; j < 8; ++j) {
        int col = wc * 128 + j * 16 + llo;
        #pragma unroll
        for (int r = 0; r < 4; ++r)
          atomicAdd(&out[(size_t)(row0 + r) * MROWS + col], acc[i][j][r]);
      }
    }
  } else {
    float* out = outp + (size_t)bidx * GRAM;
    #pragma unroll
    for (int i = 0; i < 4; ++i) {
      int row0 = wr * 64 + i * 16 + lhi * 4;
      #pragma unroll
      for (int j = 0; j < 8; ++j) {
        int col = wc * 128 + j * 16 + llo;
        #pragma unroll
        for (int r = 0; r < 4; ++r)
          out[(size_t)(row0 + r) * MROWS + col] = acc[i][j][r];
      }
    }
  }
}

// One block per batch: inverse norms from gram diagonal (sum over nchunk slices)
__global__ __launch_bounds__(256) void norms_kernel(
    const float* __restrict__ gram, float* __restrict__ norms, int nchunk)
{
  int b = blockIdx.x;
  int d = threadIdx.x;  // 0..255
  float g = 0.f;
  int c = 0;
  for (; c + 3 < nchunk; c += 4) {   // 4 independent loads in flight
    float g0 = gram[(size_t)(b * nchunk + c + 0) * GRAM + (size_t)d * (MROWS + 1)];
    float g1 = gram[(size_t)(b * nchunk + c + 1) * GRAM + (size_t)d * (MROWS + 1)];
    float g2 = gram[(size_t)(b * nchunk + c + 2) * GRAM + (size_t)d * (MROWS + 1)];
    float g3 = gram[(size_t)(b * nchunk + c + 3) * GRAM + (size_t)d * (MROWS + 1)];
    g += (g0 + g1) + (g2 + g3);
  }
  for (; c < nchunk; ++c)
    g += gram[(size_t)(b * nchunk + c) * GRAM + (size_t)d * (MROWS + 1)];
  float n = sqrtf(fmaxf(g, 0.f));
  n = fmaxf(n, 1e-12f);   // F.normalize eps
  norms[b * MROWS + d] = 1.0f / n;
}

// grid = BATCH*64; each block handles 1024 gram elements of one batch
__global__ __launch_bounds__(256) void loss_kernel(
    const float* __restrict__ gram, const float* __restrict__ norms,
    float* __restrict__ out, int nchunk)
{
  int b     = blockIdx.x >> 6;
  int strip = blockIdx.x & 63;
  int e0    = strip * 1024 + threadIdx.x * 4;
  const float* nb = norms + b * MROWS;
  const float* gp = gram + (size_t)b * nchunk * GRAM + e0;

  f32x4 g = (f32x4){0.f, 0.f, 0.f, 0.f};
  int c = 0;
  for (; c + 3 < nchunk; c += 4) {   // 4 independent loads in flight
    f32x4 v0 = *(const f32x4*)(gp + (size_t)(c + 0) * GRAM);
    f32x4 v1 = *(const f32x4*)(gp + (size_t)(c + 1) * GRAM);
    f32x4 v2 = *(const f32x4*)(gp + (size_t)(c + 2) * GRAM);
    f32x4 v3 = *(const f32x4*)(gp + (size_t)(c + 3) * GRAM);
    g += (v0 + v1) + (v2 + v3);
  }
  for (; c < nchunk; ++c)
    g += *(const f32x4*)(gp + (size_t)c * GRAM);

  int i  = e0 >> 8;
  int j0 = e0 & 255;
  float ri = nb[i];
  float accl = 0.f;
  #pragma unroll
  for (int q = 0; q < 4; ++q) {
    int j = j0 + q;
    float gh = g[q] * ri * nb[j];
    // w_i*w_j: +1 within ss / tt blocks, -1 in st / ts blocks
    float sgn = ((i < CCH) == (j < CCH)) ? 1.f : -1.f;
    accl += sgn * gh * gh;
  }
  // block reduction
  #pragma unroll
  for (int off = 32; off > 0; off >>= 1)
    accl += __shfl_down(accl, off, 64);
  __shared__ float red[4];
  if ((threadIdx.x & 63) == 0) red[threadIdx.x >> 6] = accl;
  __syncthreads();
  if (threadIdx.x == 0) {
    float t = red[0] + red[1] + red[2] + red[3];
    atomicAdd(out, t * (1.0f / (float)(BATCH * CCH * CCH)));
  }
}

extern "C" void kernel_launch(void* const* d_in, const int* in_sizes, int n_in,
                              void* d_out, int out_size, void* d_ws, size_t ws_size,
                              hipStream_t stream) {
  const float* fs = (const float*)d_in[0];
  const float* ft = (const float*)d_in[1];
  float* out = (float*)d_out;
  float* wsf = (float*)d_ws;

  float* norms = wsf;            // 16*256 floats
  float* gram  = wsf + 4096;     // partials or accumulated gram

  const size_t need_partials = ((size_t)4096 + (size_t)BATCH * NCHUNK * GRAM) * 4;
  const int atomic_mode = (ws_size >= need_partials) ? 0 : 1;
  const int nred = atomic_mode ? 1 : NCHUNK;

  static int lds_raised = 0;
  if (!lds_raised) {
    (void)hipFuncSetAttribute(reinterpret_cast<const void*>(gram_kernel),
                              hipFuncAttributeMaxDynamicSharedMemorySize, LDSBYTES);
    lds_raised = 1;
  }

  (void)hipMemsetAsync(d_out, 0, sizeof(float), stream);
  if (atomic_mode)
    (void)hipMemsetAsync(gram, 0, (size_t)BATCH * GRAM * sizeof(float), stream);

  gram_kernel<<<dim3(BATCH * NCHUNK), dim3(512), LDSBYTES, stream>>>(fs, ft, gram, atomic_mode);
  norms_kernel<<<dim3(BATCH), dim3(256), 0, stream>>>(gram, norms, nred);
  loss_kernel<<<dim3(BATCH * 64), dim3(256), 0, stream>>>(gram, norms, out, nred);
}

// Round 4
// 330.745 us; speedup vs baseline: 2.7590x; 1.0741x over previous
//
#include <hip/hip_runtime.h>

#define BATCH  16
#define CCH    128
#define TDIM   16384
#define MROWS  256                 // 2C
#define NCHUNK 16
#define KC     (TDIM / NCHUNK)     // 1024
#define BK     128                 // k-floats per step: 512 B contiguous per row visit
#define NSTEP  (KC / BK)           // 8
#define LDSH   136                 // bf16 shorts per row: 128 + 8 pad (bank-spread)
#define LDSBUF (MROWS * LDSH * 2)  // bytes per buffer (69632)
#define LDSBYTES (2 * LDSBUF)      // 139264 <= 160 KiB
#define GRAM   (MROWS * MROWS)     // 65536

typedef __attribute__((ext_vector_type(8))) short bf16x8;
typedef __attribute__((ext_vector_type(4))) float f32x4;
typedef __attribute__((ext_vector_type(4))) unsigned short u16x4;
typedef unsigned short (*ldsrow_t)[LDSH];

__device__ __forceinline__ unsigned short f2bf(float x) {
  // RTNE fp32 -> bf16 (inputs are finite normals; no NaN path needed)
  unsigned int u = __float_as_uint(x);
  u += 0x7fffu + ((u >> 16) & 1u);
  return (unsigned short)(u >> 16);
}

// Barrier without the compiler's vmcnt(0) drain: only LDS ops need
// cross-wave visibility here (global loads land in registers).
__device__ __forceinline__ void pipe_barrier() {
  asm volatile("s_waitcnt lgkmcnt(0)" ::: "memory");
  __builtin_amdgcn_s_barrier();
  asm volatile("" ::: "memory");
}

// One k-sub-block (32 k) of MFMA work from the bf16 buffer.
__device__ __forceinline__ void compute_kk(
    ldsrow_t buf, f32x4 (&acc)[4][8], int kk, int wr, int wc, int llo, int lhi)
{
  const int kcol = kk * 32 + lhi * 8;
  bf16x8 af[4], bfr[8];
  #pragma unroll
  for (int i = 0; i < 4; ++i)
    af[i] = *(const bf16x8*)&buf[wr * 64 + i * 16 + llo][kcol];
  #pragma unroll
  for (int j = 0; j < 8; ++j)
    bfr[j] = *(const bf16x8*)&buf[wc * 128 + j * 16 + llo][kcol];
  #pragma unroll
  for (int i = 0; i < 4; ++i)
    #pragma unroll
    for (int j = 0; j < 8; ++j)
      acc[i][j] = __builtin_amdgcn_mfma_f32_16x16x32_bf16(af[i], bfr[j], acc[i][j], 0, 0, 0);
}

// Stage 8 converted f32x4 (one half: fs rows or ft rows) into LDS.
// row(qq) = half*128 + qq*16 + rsub; col = seg*4 shorts (8 B per lane).
__device__ __forceinline__ void stage_half(
    ldsrow_t buf, const f32x4 (&v)[8], int half128, int rsub, int seg)
{
  #pragma unroll
  for (int qq = 0; qq < 8; ++qq) {
    u16x4 p;
    p.x = f2bf(v[qq].x); p.y = f2bf(v[qq].y);
    p.z = f2bf(v[qq].z); p.w = f2bf(v[qq].w);
    *(u16x4*)&buf[half128 + qq * 16 + rsub][seg * 4] = p;
  }
}

// Partial gram of M_b = [s_b; t_b] (256 x T) over one K-chunk.
// Global read pattern: each (row, step) visit is 512 B CONTIGUOUS
// (32 lanes x 16 B) -> 4x larger DRAM bursts than BK=32.
__global__ __launch_bounds__(512, 2) void gram_kernel(
    const float* __restrict__ fs, const float* __restrict__ ft,
    float* __restrict__ outp, int atomic_mode)
{
  extern __shared__ __attribute__((aligned(16))) char smraw[];
  ldsrow_t smA = (ldsrow_t)smraw;
  ldsrow_t smB = (ldsrow_t)(smraw + LDSBUF);

  const int tid   = threadIdx.x;
  const int bidx  = blockIdx.x;
  const int b     = bidx / NCHUNK;
  const int chunk = bidx - b * NCHUNK;
  const int kbase = chunk * KC;

  const int lane = tid & 63;
  const int w    = tid >> 6;     // wave 0..7
  const int wr   = w & 3;        // row-tile group: rows [wr*64, wr*64+64)
  const int wc   = w >> 2;       // col-tile group: cols [wc*128, wc*128+128)
  const int lhi  = lane >> 4;    // 0..3
  const int llo  = lane & 15;

  // staging geometry: 512 threads x 16 loads/step = 256 rows x 32 segs
  const int rsub = tid >> 5;     // 0..15: row within each 16-row group
  const int seg  = tid & 31;     // 16-B segment within the row's 512 B

  const float* base_fs = fs + (size_t)(b * CCH + rsub) * TDIM + kbase + seg * 4;
  const float* base_ft = ft + (size_t)(b * CCH + rsub) * TDIM + kbase + seg * 4;

  f32x4 acc[4][8];
  #pragma unroll
  for (int i = 0; i < 4; ++i)
    #pragma unroll
    for (int j = 0; j < 8; ++j)
      acc[i][j] = (f32x4){0.f, 0.f, 0.f, 0.f};

  f32x4 vA[8], vB[8];

  // prologue: stage step 0 into smA
  #pragma unroll
  for (int qq = 0; qq < 8; ++qq)
    vA[qq] = *(const f32x4*)(base_fs + (size_t)qq * 16 * TDIM);
  #pragma unroll
  for (int qq = 0; qq < 8; ++qq)
    vB[qq] = *(const f32x4*)(base_ft + (size_t)qq * 16 * TDIM);
  stage_half(smA, vA, 0,   rsub, seg);
  stage_half(smA, vB, 128, rsub, seg);
  pipe_barrier();

  ldsrow_t curb = smA, nxtb = smB;
  #pragma unroll 1
  for (int s = 0; s < NSTEP - 1; ++s) {
    // prefetch step s+1 (halves), interleaved with compute of step s
    #pragma unroll
    for (int qq = 0; qq < 8; ++qq)
      vA[qq] = *(const f32x4*)(base_fs + (size_t)qq * 16 * TDIM + (s + 1) * BK);
    compute_kk(curb, acc, 0, wr, wc, llo, lhi);
    compute_kk(curb, acc, 1, wr, wc, llo, lhi);
    #pragma unroll
    for (int qq = 0; qq < 8; ++qq)
      vB[qq] = *(const f32x4*)(base_ft + (size_t)qq * 16 * TDIM + (s + 1) * BK);
    stage_half(nxtb, vA, 0, rsub, seg);     // waits vA only (counted)
    compute_kk(curb, acc, 2, wr, wc, llo, lhi);
    compute_kk(curb, acc, 3, wr, wc, llo, lhi);
    stage_half(nxtb, vB, 128, rsub, seg);   // waits vB only
    pipe_barrier();
    ldsrow_t t = curb; curb = nxtb; nxtb = t;
  }
  // last step: compute only
  compute_kk(curb, acc, 0, wr, wc, llo, lhi);
  compute_kk(curb, acc, 1, wr, wc, llo, lhi);
  compute_kk(curb, acc, 2, wr, wc, llo, lhi);
  compute_kk(curb, acc, 3, wr, wc, llo, lhi);

  // epilogue: write partial gram
  // C/D layout (m89/m91 verified): col = lane&15, row = (lane>>4)*4 + reg
  if (atomic_mode) {
    float* out = outp + (size_t)b * GRAM;
    #pragma unroll
    for (int i = 0; i < 4; ++i) {
      int row0 = wr * 64 + i * 16 + lhi * 4;
      #pragma unroll
      for (int j = 0; j < 8; ++j) {
        int col = wc * 128 + j * 16 + llo;
        #pragma unroll
        for (int r = 0; r < 4; ++r)
          atomicAdd(&out[(size_t)(row0 + r) * MROWS + col], acc[i][j][r]);
      }
    }
  } else {
    float* out = outp + (size_t)bidx * GRAM;
    #pragma unroll
    for (int i = 0; i < 4; ++i) {
      int row0 = wr * 64 + i * 16 + lhi * 4;
      #pragma unroll
      for (int j = 0; j < 8; ++j) {
        int col = wc * 128 + j * 16 + llo;
        #pragma unroll
        for (int r = 0; r < 4; ++r)
          out[(size_t)(row0 + r) * MROWS + col] = acc[i][j][r];
      }
    }
  }
}

// One block per batch: inverse norms from gram diagonal (sum over nchunk slices)
__global__ __launch_bounds__(256) void norms_kernel(
    const float* __restrict__ gram, float* __restrict__ norms, int nchunk)
{
  int b = blockIdx.x;
  int d = threadIdx.x;  // 0..255
  float g = 0.f;
  int c = 0;
  for (; c + 3 < nchunk; c += 4) {   // 4 independent loads in flight
    float g0 = gram[(size_t)(b * nchunk + c + 0) * GRAM + (size_t)d * (MROWS + 1)];
    float g1 = gram[(size_t)(b * nchunk + c + 1) * GRAM + (size_t)d * (MROWS + 1)];
    float g2 = gram[(size_t)(b * nchunk + c + 2) * GRAM + (size_t)d * (MROWS + 1)];
    float g3 = gram[(size_t)(b * nchunk + c + 3) * GRAM + (size_t)d * (MROWS + 1)];
    g += (g0 + g1) + (g2 + g3);
  }
  for (; c < nchunk; ++c)
    g += gram[(size_t)(b * nchunk + c) * GRAM + (size_t)d * (MROWS + 1)];
  float n = sqrtf(fmaxf(g, 0.f));
  n = fmaxf(n, 1e-12f);   // F.normalize eps
  norms[b * MROWS + d] = 1.0f / n;
}

// grid = BATCH*64; each block handles 1024 gram elements of one batch
__global__ __launch_bounds__(256) void loss_kernel(
    const float* __restrict__ gram, const float* __restrict__ norms,
    float* __restrict__ out, int nchunk)
{
  int b     = blockIdx.x >> 6;
  int strip = blockIdx.x & 63;
  int e0    = strip * 1024 + threadIdx.x * 4;
  const float* nb = norms + b * MROWS;
  const float* gp = gram + (size_t)b * nchunk * GRAM + e0;

  f32x4 g = (f32x4){0.f, 0.f, 0.f, 0.f};
  int c = 0;
  for (; c + 3 < nchunk; c += 4) {   // 4 independent loads in flight
    f32x4 v0 = *(const f32x4*)(gp + (size_t)(c + 0) * GRAM);
    f32x4 v1 = *(const f32x4*)(gp + (size_t)(c + 1) * GRAM);
    f32x4 v2 = *(const f32x4*)(gp + (size_t)(c + 2) * GRAM);
    f32x4 v3 = *(const f32x4*)(gp + (size_t)(c + 3) * GRAM);
    g += (v0 + v1) + (v2 + v3);
  }
  for (; c < nchunk; ++c)
    g += *(const f32x4*)(gp + (size_t)c * GRAM);

  int i  = e0 >> 8;
  int j0 = e0 & 255;
  float ri = nb[i];
  float accl = 0.f;
  #pragma unroll
  for (int q = 0; q < 4; ++q) {
    int j = j0 + q;
    float gh = g[q] * ri * nb[j];
    // w_i*w_j: +1 within ss / tt blocks, -1 in st / ts blocks
    float sgn = ((i < CCH) == (j < CCH)) ? 1.f : -1.f;
    accl += sgn * gh * gh;
  }
  // block reduction
  #pragma unroll
  for (int off = 32; off > 0; off >>= 1)
    accl += __shfl_down(accl, off, 64);
  __shared__ float red[4];
  if ((threadIdx.x & 63) == 0) red[threadIdx.x >> 6] = accl;
  __syncthreads();
  if (threadIdx.x == 0) {
    float t = red[0] + red[1] + red[2] + red[3];
    atomicAdd(out, t * (1.0f / (float)(BATCH * CCH * CCH)));
  }
}

extern "C" void kernel_launch(void* const* d_in, const int* in_sizes, int n_in,
                              void* d_out, int out_size, void* d_ws, size_t ws_size,
                              hipStream_t stream) {
  const float* fs = (const float*)d_in[0];
  const float* ft = (const float*)d_in[1];
  float* out = (float*)d_out;
  float* wsf = (float*)d_ws;

  float* norms = wsf;            // 16*256 floats
  float* gram  = wsf + 4096;     // partials or accumulated gram

  const size_t need_partials = ((size_t)4096 + (size_t)BATCH * NCHUNK * GRAM) * 4;
  const int atomic_mode = (ws_size >= need_partials) ? 0 : 1;
  const int nred = atomic_mode ? 1 : NCHUNK;

  static int lds_raised = 0;
  if (!lds_raised) {
    (void)hipFuncSetAttribute(reinterpret_cast<const void*>(gram_kernel),
                              hipFuncAttributeMaxDynamicSharedMemorySize, LDSBYTES);
    lds_raised = 1;
  }

  (void)hipMemsetAsync(d_out, 0, sizeof(float), stream);
  if (atomic_mode)
    (void)hipMemsetAsync(gram, 0, (size_t)BATCH * GRAM * sizeof(float), stream);

  gram_kernel<<<dim3(BATCH * NCHUNK), dim3(512), LDSBYTES, stream>>>(fs, ft, gram, atomic_mode);
  norms_kernel<<<dim3(BATCH), dim3(256), 0, stream>>>(gram, norms, nred);
  loss_kernel<<<dim3(BATCH * 64), dim3(256), 0, stream>>>(gram, norms, out, nred);
}